// Round 3
// baseline (102.902 us; speedup 1.0000x reference)
//
#include <hip/hip_runtime.h>
#include <math.h>

// SetConvEncoder: out[b][ch][gy][gx] = sum_n EX[gx,n]*EY[gy,n]*y4[n,ch]
//  EX[gx,n] = exp2(cc*(gx/W - xn)^2), EY likewise in y; cc = -0.5*log2(e)/ls^2
//  y4 = {y0*m, y1*m, y2*m, m}  (mask folded into channels; ch3 = density)
// Separable-Gaussian reformulation: 4 fp32 FMAs per (grid,ctx) pair instead of
// 9 ops + exp. VALU-bound: 1.07G FMA ~ 13.7us floor.
//
// R1: sEX 16B-group XOR swizzle (4-way -> 2-way = free), staging hoists.
// R2: replace 4.2M-fp32-atomicAdd epilogue (est. 7-28us TCC serialization tail)
//     with plain float4 partial stores to d_ws + reduction kernel (~6us determ.);
//     atomic path kept as fallback if ws_size is too small.

constexpr int BB = 8;
constexpr int NN = 2048;
constexpr int GH = 128;
constexpr int GW = 128;
constexpr int GY_TILE = 16;   // gy rows per block
constexpr int KSPLIT  = 8;    // context split across blocks
constexpr int NK = NN / KSPLIT;  // 256 ctx points per block
constexpr int NC = 32;           // ctx chunk staged in LDS
constexpr int OUTSZ = BB * 4 * GH * GW;  // 524288 floats per partial slice

__device__ __forceinline__ int swz_col(int gx) {
    // 16B-group swizzle: group g=gx>>2, slot = g ^ bit4(g); keeps 4-dword groups
    // contiguous (float4-readable) while spreading the tx*8-stride read pattern
    // over all 8 bank-quads (2-way max = free).
    int g = gx >> 2;
    return (((g ^ ((g >> 4) & 1)) << 2) | (gx & 3));
}

template <bool ATOMIC>
__global__ __launch_bounds__(256, 2) void setconv_fused(
    const float* __restrict__ xc,    // [B,N,2]
    const float* __restrict__ yc,    // [B,N,3]
    const float* __restrict__ mask,  // [B,N]
    const float* __restrict__ logls, // [1]
    const float* __restrict__ grid,  // [H,W,2]
    float* __restrict__ dst)         // ATOMIC: out[B,4,H,W] (zeroed)
                                     // else:   partials [KSPLIT][B,4,H,W]
{
    __shared__ float sEX[NC][GW];          // 16 KB (column-swizzled)
    __shared__ float sYT[NC][GY_TILE][4];  //  8 KB

    const int ks  = blockIdx.x;   // k-split index
    const int gyt = blockIdx.y;   // gy tile
    const int b   = blockIdx.z;   // batch
    const int tid = threadIdx.x;
    const int tx  = tid & 15;     // gx octet: gx = tx*8 .. tx*8+7
    const int ty  = tid >> 4;     // gy within tile

    const float ls = __expf(logls[0]);
    const float cc = -0.72134752044f / (ls * ls);  // -0.5*log2(e)/ls^2

    const int n_base = ks * NK;

    // ---- staging-loop thread-constants (hoisted) ----
    // EX staging: i = r*256+tid -> gx = tid&127 (const), nl = 2r + (tid>>7)
    const int   gxs  = tid & 127;
    const int   hi   = tid >> 7;                 // 0 or 1
    const float gxv  = grid[gxs * 2 + 0];        // xx at row 0
    const int   colx = swz_col(gxs);
    // YT staging: i = r*256+tid -> gy = tid&15 (const), nl = 16r + (tid>>4)
    const int   gyl  = tid & 15;
    const int   nlo  = tid >> 4;                 // 0..15
    const float gyv  = grid[((gyt * GY_TILE + gyl) * GW) * 2 + 1];  // yy at col 0

    // swizzled read columns for the inner loop (thread-constant)
    const int colA = swz_col(tx * 8);            // first float4
    const int colB = swz_col(tx * 8 + 4);        // second float4

    float acc[8][4];
#pragma unroll
    for (int j = 0; j < 8; ++j)
#pragma unroll
        for (int c = 0; c < 4; ++c) acc[j][c] = 0.0f;

    for (int ch = 0; ch < NK; ch += NC) {
        __syncthreads();  // protect LDS from previous chunk's readers

        // ---- stage EX: NC*GW = 4096 entries, 16 per thread ----
#pragma unroll
        for (int r = 0; r < (NC * GW) / 256; ++r) {
            int nl = 2 * r + hi;
            int n  = n_base + ch + nl;
            float xn = xc[(b * NN + n) * 2 + 0];
            float dx = gxv - xn;
            sEX[nl][colx] = exp2f(cc * dx * dx);
        }
        // ---- stage YT: NC*GY_TILE = 512 entries (x4 ch), 2 per thread ----
#pragma unroll
        for (int r = 0; r < (NC * GY_TILE) / 256; ++r) {
            int nl = r * 16 + nlo;
            int n  = n_base + ch + nl;
            float yn  = xc[(b * NN + n) * 2 + 1];
            float dy  = gyv - yn;
            float ey  = exp2f(cc * dy * dy);
            float m   = mask[b * NN + n];
            float eym = ey * m;
            sYT[nl][gyl][0] = eym * yc[(b * NN + n) * 3 + 0];
            sYT[nl][gyl][1] = eym * yc[(b * NN + n) * 3 + 1];
            sYT[nl][gyl][2] = eym * yc[(b * NN + n) * 3 + 2];
            sYT[nl][gyl][3] = eym;  // density channel
        }
        __syncthreads();

        // ---- accumulate: 32 FMAs + 3 ds_read_b128 per n ----
#pragma unroll
        for (int nl = 0; nl < NC; ++nl) {
            float4 yt = *(const float4*)&sYT[nl][ty][0];
            float4 ea = *(const float4*)&sEX[nl][colA];
            float4 eb = *(const float4*)&sEX[nl][colB];
            float ex[8] = {ea.x, ea.y, ea.z, ea.w, eb.x, eb.y, eb.z, eb.w};
#pragma unroll
            for (int j = 0; j < 8; ++j) {
                acc[j][0] = fmaf(ex[j], yt.x, acc[j][0]);
                acc[j][1] = fmaf(ex[j], yt.y, acc[j][1]);
                acc[j][2] = fmaf(ex[j], yt.z, acc[j][2]);
                acc[j][3] = fmaf(ex[j], yt.w, acc[j][3]);
            }
        }
    }

    // ---- epilogue ----
    const int gy = gyt * GY_TILE + ty;
    if (ATOMIC) {
#pragma unroll
        for (int c = 0; c < 4; ++c)
#pragma unroll
            for (int j = 0; j < 8; ++j)
                atomicAdd(&dst[(((b * 4 + c) * GH) + gy) * GW + tx * 8 + j],
                          acc[j][c]);
    } else {
        // plain coalesced float4 stores into this split's partial slice
        float* slice = dst + (size_t)ks * OUTSZ;
#pragma unroll
        for (int c = 0; c < 4; ++c) {
            int base = (((b * 4 + c) * GH) + gy) * GW + tx * 8;
            float4 v0 = {acc[0][c], acc[1][c], acc[2][c], acc[3][c]};
            float4 v1 = {acc[4][c], acc[5][c], acc[6][c], acc[7][c]};
            *(float4*)&slice[base]     = v0;
            *(float4*)&slice[base + 4] = v1;
        }
    }
}

__global__ __launch_bounds__(256) void setconv_reduce(
    const float* __restrict__ pw,  // [KSPLIT][OUTSZ]
    float* __restrict__ out)       // [OUTSZ]
{
    const int n4 = OUTSZ / 4;  // float4 count per slice
    int i = blockIdx.x * 256 + threadIdx.x;
    if (i >= n4) return;
    const float4* p = (const float4*)pw;
    float4 s = p[i];
#pragma unroll
    for (int k = 1; k < KSPLIT; ++k) {
        float4 v = p[(size_t)k * n4 + i];
        s.x += v.x; s.y += v.y; s.z += v.z; s.w += v.w;
    }
    ((float4*)out)[i] = s;
}

extern "C" void kernel_launch(void* const* d_in, const int* in_sizes, int n_in,
                              void* d_out, int out_size, void* d_ws, size_t ws_size,
                              hipStream_t stream) {
    const float* xc    = (const float*)d_in[0];  // x_context [8,2048,2]
    const float* yc    = (const float*)d_in[1];  // y_context [8,2048,3]
    const float* mask  = (const float*)d_in[2];  // context_mask [8,2048]
    const float* logls = (const float*)d_in[3];  // log_lengthscale [1]
    const float* grid  = (const float*)d_in[4];  // grid [128,128,2]
    float* out = (float*)d_out;                  // [8,4,128,128]

    dim3 grid_dim(KSPLIT, GH / GY_TILE, BB);  // (8, 8, 8) = 512 blocks
    const size_t need = (size_t)KSPLIT * OUTSZ * sizeof(float);  // 16 MB

    if (ws_size >= need) {
        // deterministic path: partials in d_ws + reduction (no atomics, no memset)
        float* pw = (float*)d_ws;
        setconv_fused<false><<<grid_dim, 256, 0, stream>>>(xc, yc, mask, logls,
                                                           grid, pw);
        setconv_reduce<<<dim3(OUTSZ / 4 / 256), 256, 0, stream>>>(pw, out);
    } else {
        // fallback: zero + atomicAdd combine
        hipMemsetAsync(out, 0, (size_t)out_size * sizeof(float), stream);
        setconv_fused<true><<<grid_dim, 256, 0, stream>>>(xc, yc, mask, logls,
                                                          grid, out);
    }
}

// Round 7
// 89.427 us; speedup vs baseline: 1.1507x; 1.1507x over previous
//
#include <hip/hip_runtime.h>
#include <hip/hip_bf16.h>
#include <math.h>

// SetConvEncoder via separable Gaussian + split-bf16 MFMA.
//  out[b][ch][gy][gx] = sum_n EX[n][gx]*EY[n][gy]*y4[n][ch]
//  = GEMM C[m=4*gy+ch][gx] += sum_k A[k][m]*B[k][n],  A=YT=EY*y4, B=EX
// R3 post-mortem: scalar path was LDS-ISSUE-bound (VALUBusy 44% == 64/144 model;
// 1.57M ds_read_b128 ~= 31us of LDS pipe). MFMA frag reuse cuts reads ~8x.
// Split-bf16 (hi+lo, 3 MFMAs: Ah*Bh + Ah*Bl + Al*Bh) keeps ~17 mantissa bits
// -> ~2e-3 abs error on O(100) outputs.
// k-slot layout: A and B panels stored with the SAME bijective (lane-group,j)->k
// map, so any HW k-permutation cancels in the K-sum; load-bearing assumptions are
// only (1) A row = lane&15 / B col = lane&15 symmetry, (2) the m89-verified C/D
// map col=lane&15, row=(lane>>4)*4+reg.
// R6: re-audited (bijectivity, addressing, coverage, alignment, poison-safety);
// resubmitted unchanged -- R5 never ran (infra).

typedef float f32x4 __attribute__((ext_vector_type(4)));
typedef short s16x8 __attribute__((ext_vector_type(8)));

constexpr int BB = 8, NN = 2048, GH = 128, GW = 128;
constexpr int GY_TILE = 16;          // block covers 16 gy -> M = 64 rows
constexpr int KSPLIT  = 8;           // grid (8,8,8) = 512 blocks
constexpr int NK      = NN / KSPLIT; // 256 ctx points per block
constexpr int NCH     = NK / 32;     // 8 K-chunks of 32
constexpr int OUTSZ   = BB * 4 * GH * GW;  // 524288 floats per partial slice

// split v into bf16 hi + bf16 lo (lo = bf16(v - float(hi))); pack two values
// (k0, k0+1) into one u32 per panel (low u16 = k0).
__device__ __forceinline__ void split2(float v0, float v1,
                                       unsigned& hi, unsigned& lo) {
    __hip_bfloat16 a = __float2bfloat16(v0);
    __hip_bfloat16 b = __float2bfloat16(v1);
    float fa = __bfloat162float(a), fb = __bfloat162float(b);
    __hip_bfloat16 ra = __float2bfloat16(v0 - fa);
    __hip_bfloat16 rb = __float2bfloat16(v1 - fb);
    unsigned short ua, ub, uc, ud;
    __builtin_memcpy(&ua, &a, 2);  __builtin_memcpy(&ub, &b, 2);
    __builtin_memcpy(&uc, &ra, 2); __builtin_memcpy(&ud, &rb, 2);
    hi = (unsigned)ua | ((unsigned)ub << 16);
    lo = (unsigned)uc | ((unsigned)ud << 16);
}

template <bool ATOMIC>
__global__ __launch_bounds__(256, 2) void setconv_mfma(
    const float* __restrict__ xc,    // [B,N,2]
    const float* __restrict__ yc,    // [B,N,3]
    const float* __restrict__ mask,  // [B,N]
    const float* __restrict__ logls, // [1]
    const float* __restrict__ grid,  // [H,W,2]
    float* __restrict__ dst)         // ATOMIC: out (zeroed); else partials [KS][OUTSZ]
{
    // frag-order panels: u32 slot s -> lane-row q=s>>2 (tile=q>>6, lane=q&63),
    // jp=s&3 (bf16 elems 2jp,2jp+1). One lane-row = 4 u32 = 16B = one s16x8 frag.
    __shared__ unsigned sA[2][4 * 64 * 4];   // [hi/lo][M=64 x K=32]  4 KB each
    __shared__ unsigned sB[2][8 * 64 * 4];   // [hi/lo][N=128 x K=32] 8 KB each

    const int ks  = blockIdx.x;
    const int gyt = blockIdx.y;
    const int b   = blockIdx.z;
    const int tid = threadIdx.x;
    const int l   = tid & 63;   // lane
    const int w   = tid >> 6;   // wave 0..3

    const float ls = __expf(logls[0]);
    const float cc = -0.72134752044f / (ls * ls);  // -0.5*log2(e)/ls^2

    // ---- staging decode (thread-constant) ----
    // slot s = r*256+tid -> lane_s = tid>>2, jp = tid&3, tile = r
    const int lane_s = tid >> 2;
    const int jp     = tid & 3;
    const int sb15   = lane_s & 15;            // n%16 (B) or m%16 (A)
    const int kg     = lane_s >> 4;            // k-group 0..3
    const int k0     = ((jp >> 1) << 4) | (kg << 2) | ((jp & 1) << 1); // even
    const int ch     = sb15 & 3;               // A: channel
    const int gyb    = sb15 >> 2;              // A: gy%4 base

    // hoisted grid coordinates (loop-invariant)
    float gxv[8];
#pragma unroll
    for (int r = 0; r < 8; ++r) gxv[r] = grid[(r * 16 + sb15) * 2 + 0];
    float gyv[4];
#pragma unroll
    for (int r = 0; r < 4; ++r)
        gyv[r] = grid[(size_t)(gyt * GY_TILE + r * 4 + gyb) * GW * 2 + 1];

    // wave tile: 2 m-tiles x 4 n-tiles of 16x16
    const int mtb = (w & 1) * 2;
    const int ntb = (w >> 1) * 4;

    f32x4 acc[2][4];
#pragma unroll
    for (int i = 0; i < 2; ++i)
#pragma unroll
        for (int j = 0; j < 4; ++j) acc[i][j] = (f32x4){0.f, 0.f, 0.f, 0.f};

    const int nb0 = b * NN + ks * NK;

    for (int chn = 0; chn < NCH; ++chn) {
        const int kbase = nb0 + chn * 32 + k0;  // even -> 16B-aligned xc pair
        const float4 xy = *(const float4*)&xc[(size_t)kbase * 2]; // x0,y0,x1,y1
        const float2 mk = *(const float2*)&mask[kbase];
        float yv0 = 0.f, yv1 = 0.f;
        if (ch < 3) {
            yv0 = yc[(size_t)kbase * 3 + ch];
            yv1 = yc[(size_t)(kbase + 1) * 3 + ch];
        }
        const float y40 = (ch < 3) ? yv0 * mk.x : mk.x;
        const float y41 = (ch < 3) ? yv1 * mk.y : mk.y;

        __syncthreads();  // previous chunk's frag reads done

        // ---- stage B = EX (8 n-tiles): conflict-free consecutive-u32 writes ----
#pragma unroll
        for (int r = 0; r < 8; ++r) {
            float d0 = gxv[r] - xy.x, d1 = gxv[r] - xy.z;
            float v0 = exp2f(cc * d0 * d0), v1 = exp2f(cc * d1 * d1);
            unsigned hi, lo;
            split2(v0, v1, hi, lo);
            sB[0][r * 256 + tid] = hi;
            sB[1][r * 256 + tid] = lo;
        }
        // ---- stage A = YT (4 m-tiles) ----
#pragma unroll
        for (int r = 0; r < 4; ++r) {
            float d0 = gyv[r] - xy.y, d1 = gyv[r] - xy.w;
            float e0 = exp2f(cc * d0 * d0) * y40;
            float e1 = exp2f(cc * d1 * d1) * y41;
            unsigned hi, lo;
            split2(e0, e1, hi, lo);
            sA[0][r * 256 + tid] = hi;
            sA[1][r * 256 + tid] = lo;
        }
        __syncthreads();

        // ---- fragments + 24 MFMAs ----
        const s16x8* pAh = (const s16x8*)sA[0];
        const s16x8* pAl = (const s16x8*)sA[1];
        const s16x8* pBh = (const s16x8*)sB[0];
        const s16x8* pBl = (const s16x8*)sB[1];
        s16x8 ah[2], al[2], bh[4], bl[4];
#pragma unroll
        for (int i = 0; i < 2; ++i) {
            ah[i] = pAh[(mtb + i) * 64 + l];
            al[i] = pAl[(mtb + i) * 64 + l];
        }
#pragma unroll
        for (int j = 0; j < 4; ++j) {
            bh[j] = pBh[(ntb + j) * 64 + l];
            bl[j] = pBl[(ntb + j) * 64 + l];
        }
#pragma unroll
        for (int i = 0; i < 2; ++i)
#pragma unroll
            for (int j = 0; j < 4; ++j) {
                acc[i][j] = __builtin_amdgcn_mfma_f32_16x16x32_bf16(
                    ah[i], bh[j], acc[i][j], 0, 0, 0);
                acc[i][j] = __builtin_amdgcn_mfma_f32_16x16x32_bf16(
                    ah[i], bl[j], acc[i][j], 0, 0, 0);
                acc[i][j] = __builtin_amdgcn_mfma_f32_16x16x32_bf16(
                    al[i], bh[j], acc[i][j], 0, 0, 0);
            }
    }

    // ---- epilogue: C/D map col=l&15 (gx), row=(l>>4)*4+reg (m=4*gy+ch) ----
    const int colg = l & 15, rowg = l >> 4;
    float* slice = ATOMIC ? dst : dst + (size_t)ks * OUTSZ;
#pragma unroll
    for (int i = 0; i < 2; ++i) {
        const int gy = gyt * GY_TILE + (mtb + i) * 4 + rowg;
#pragma unroll
        for (int j = 0; j < 4; ++j) {
            const int gx = (ntb + j) * 16 + colg;
#pragma unroll
            for (int r = 0; r < 4; ++r) {  // r == channel
                const size_t off = (((size_t)(b * 4 + r)) * GH + gy) * GW + gx;
                if (ATOMIC) atomicAdd(&slice[off], acc[i][j][r]);
                else        slice[off] = acc[i][j][r];
            }
        }
    }
}

__global__ __launch_bounds__(256, 8) void setconv_reduce(
    const float* __restrict__ pw,  // [KSPLIT][OUTSZ]
    float* __restrict__ out)       // [OUTSZ]
{
    const int n4 = OUTSZ / 4;
    const int stride = gridDim.x * 256;
    const float4* p = (const float4*)pw;
    for (int i = blockIdx.x * 256 + threadIdx.x; i < n4; i += stride) {
        float4 s = p[i];
#pragma unroll
        for (int k = 1; k < KSPLIT; ++k) {
            float4 v = p[(size_t)k * n4 + i];
            s.x += v.x; s.y += v.y; s.z += v.z; s.w += v.w;
        }
        ((float4*)out)[i] = s;
    }
}

extern "C" void kernel_launch(void* const* d_in, const int* in_sizes, int n_in,
                              void* d_out, int out_size, void* d_ws, size_t ws_size,
                              hipStream_t stream) {
    const float* xc    = (const float*)d_in[0];  // x_context [8,2048,2]
    const float* yc    = (const float*)d_in[1];  // y_context [8,2048,3]
    const float* mask  = (const float*)d_in[2];  // context_mask [8,2048]
    const float* logls = (const float*)d_in[3];  // log_lengthscale [1]
    const float* grid  = (const float*)d_in[4];  // grid [128,128,2]
    float* out = (float*)d_out;                  // [8,4,128,128]

    dim3 gdim(KSPLIT, GH / GY_TILE, BB);  // (8,8,8) = 512 blocks
    const size_t need = (size_t)KSPLIT * OUTSZ * sizeof(float);  // 16 MB

    if (ws_size >= need) {
        float* pw = (float*)d_ws;
        setconv_mfma<false><<<gdim, 256, 0, stream>>>(xc, yc, mask, logls,
                                                      grid, pw);
        setconv_reduce<<<dim3(512), 256, 0, stream>>>(pw, out);
    } else {
        hipMemsetAsync(out, 0, (size_t)out_size * sizeof(float), stream);
        setconv_mfma<true><<<gdim, 256, 0, stream>>>(xc, yc, mask, logls,
                                                     grid, out);
    }
}